// Round 1
// baseline (194.589 us; speedup 1.0000x reference)
//
#include <hip/hip_runtime.h>
#include <utility>

#define T_LEN 2048

// --- cross-lane helpers -----------------------------------------------------
// DPP row rotate (16-lane rows). Direction is probed at runtime in the kernel.
template<int S>
__device__ __forceinline__ float rot16(float v) {
  if constexpr (S == 0) {
    return v;
  } else {
    int r = __builtin_amdgcn_update_dpp(0, __float_as_int(v), 0x120 + S, 0xF, 0xF, true);
    return __int_as_float(r);
  }
}

// ds_swizzle BitMode broadcast: src_lane = (lane & 0x10) | S  (per 32-lane half)
// offset = (xor<<10) | (or<<5) | and  ->  (S<<5) | 0x10
template<int S>
__device__ __forceinline__ float bcast16(float v) {
  return __int_as_float(__builtin_amdgcn_ds_swizzle(__float_as_int(v), (S << 5) | 0x10));
}

__device__ __forceinline__ float xor_swz(float v, int imm_offset_unused) { return v; }

// --- one timestep -----------------------------------------------------------
// h_new[j] = relu( x_t*W_ih[j] + b_ih[j] + b_hh[j] + sum_k W_hh[j,k]*h[k] )
// dot computed as sum over rotations: w[s] = W_hh[j][sigma_s(j)] preloaded.
template<int S>
__device__ __forceinline__ void substep(float& h, float xv, const float (&w)[16],
                                        float wih, float bias) {
  float xb = bcast16<S>(xv);               // broadcast lane S's x within group
  float a0 = fmaf(xb, wih, bias);
  a0 = fmaf(rot16<0>(h),  w[0],  a0);
  float a1 = rot16<1>(h)  * w[1];
  float a2 = rot16<2>(h)  * w[2];
  float a3 = rot16<3>(h)  * w[3];
  a0 = fmaf(rot16<4>(h),  w[4],  a0);
  a1 = fmaf(rot16<5>(h),  w[5],  a1);
  a2 = fmaf(rot16<6>(h),  w[6],  a2);
  a3 = fmaf(rot16<7>(h),  w[7],  a3);
  a0 = fmaf(rot16<8>(h),  w[8],  a0);
  a1 = fmaf(rot16<9>(h),  w[9],  a1);
  a2 = fmaf(rot16<10>(h), w[10], a2);
  a3 = fmaf(rot16<11>(h), w[11], a3);
  a0 = fmaf(rot16<12>(h), w[12], a0);
  a1 = fmaf(rot16<13>(h), w[13], a1);
  a2 = fmaf(rot16<14>(h), w[14], a2);
  a3 = fmaf(rot16<15>(h), w[15], a3);
  h = fmaxf((a0 + a1) + (a2 + a3), 0.0f);
}

template<int... Ss>
__device__ __forceinline__ void chunk16(float& h, float xv, const float (&w)[16],
                                        float wih, float bias,
                                        std::integer_sequence<int, Ss...>) {
  (substep<Ss>(h, xv, w, wih, bias), ...);
}

// --- kernel -----------------------------------------------------------------
__global__ __launch_bounds__(256) void rnn_relu_kernel(
    const float* __restrict__ x, const float* __restrict__ W_ih,
    const float* __restrict__ b_ih, const float* __restrict__ W_hh,
    const float* __restrict__ b_hh, const float* __restrict__ W_fc,
    const float* __restrict__ b_fc, float* __restrict__ out) {
  const int tid = threadIdx.x;
  const int j   = tid & 15;                 // h index owned by this lane
  const int b   = blockIdx.x * 16 + (tid >> 4);  // batch element (group of 16 lanes)

  // Probe DPP row_ror:1 direction: lane j receives either (j+1)&15 or (j-1)&15.
  int pr = __builtin_amdgcn_update_dpp(0, j, 0x121, 0xF, 0xF, true);
  const bool plus = (pr == ((j + 1) & 15));

  // Rotated weight table matching the probed direction:
  // rot16<s>(h) delivers h[(j + dir*s) & 15]  ->  w[s] = W_hh[j][(j + dir*s) & 15]
  float w[16];
#pragma unroll
  for (int s = 0; s < 16; ++s) {
    int k = (j + (plus ? s : (16 - s))) & 15;
    w[s] = W_hh[j * 16 + k];
  }
  const float wih  = W_ih[j];
  const float bias = b_ih[j] + b_hh[j];

  const float* __restrict__ xrow = x + (size_t)b * T_LEN;

  float h  = 0.0f;
  float xv = xrow[j];                       // chunk 0: lane j holds x[b, j]
#pragma unroll 1
  for (int t0 = 0; t0 < T_LEN; t0 += 16) {
    float xnext = 0.0f;
    if (t0 + 16 < T_LEN) xnext = xrow[t0 + 16 + j];   // prefetch next chunk
    chunk16(h, xv, w, wih, bias, std::make_integer_sequence<int, 16>{});
    xv = xnext;
  }

  // Epilogue: out[b, c] = sum_j h[j] * W_fc[c, j] + b_fc[c]
  float p0 = h * W_fc[j];
  float p1 = h * W_fc[16 + j];
  // xor-butterfly reduce across the 16-lane group (BitMode: and=0x1F, xor=d)
  p0 += __int_as_float(__builtin_amdgcn_ds_swizzle(__float_as_int(p0), 0x041F));
  p1 += __int_as_float(__builtin_amdgcn_ds_swizzle(__float_as_int(p1), 0x041F));
  p0 += __int_as_float(__builtin_amdgcn_ds_swizzle(__float_as_int(p0), 0x081F));
  p1 += __int_as_float(__builtin_amdgcn_ds_swizzle(__float_as_int(p1), 0x081F));
  p0 += __int_as_float(__builtin_amdgcn_ds_swizzle(__float_as_int(p0), 0x101F));
  p1 += __int_as_float(__builtin_amdgcn_ds_swizzle(__float_as_int(p1), 0x101F));
  p0 += __int_as_float(__builtin_amdgcn_ds_swizzle(__float_as_int(p0), 0x201F));
  p1 += __int_as_float(__builtin_amdgcn_ds_swizzle(__float_as_int(p1), 0x201F));

  if (j == 0) {
    out[b * 2 + 0] = p0 + b_fc[0];
    out[b * 2 + 1] = p1 + b_fc[1];
  }
}

// --- launch -----------------------------------------------------------------
extern "C" void kernel_launch(void* const* d_in, const int* in_sizes, int n_in,
                              void* d_out, int out_size, void* d_ws, size_t ws_size,
                              hipStream_t stream) {
  const float* x    = (const float*)d_in[0];
  const float* W_ih = (const float*)d_in[1];
  const float* b_ih = (const float*)d_in[2];
  const float* W_hh = (const float*)d_in[3];
  const float* b_hh = (const float*)d_in[4];
  const float* W_fc = (const float*)d_in[5];
  const float* b_fc = (const float*)d_in[6];
  float* out = (float*)d_out;

  const int B = 4096;
  dim3 grid(B / 16);   // 256 blocks -> 1 block/CU, 4 waves/CU (1 per SIMD)
  dim3 block(256);
  hipLaunchKernelGGL(rnn_relu_kernel, grid, block, 0, stream,
                     x, W_ih, b_ih, W_hh, b_hh, W_fc, b_fc, out);
}

// Round 2
// 108.992 us; speedup vs baseline: 1.7854x; 1.7854x over previous
//
#include <hip/hip_runtime.h>

#define T_LEN 2048

typedef float f4 __attribute__((ext_vector_type(4)));

// --- one timestep, fully scheduled by hand ----------------------------------
// h_new[j] = relu( x_t*wih[j] + bias[j] + sum_k W_hh[j,k]*h[k] )
// Rotation form: sum_s w[s] * ror_s(h), w[s] preloaded to match probed HW
// direction of row_ror. 4 independent accumulator chains; DPP hazard
// (VALU write of h -> DPP read of h needs 2 wait states) is satisfied because
// the first two instructions of each block do not DPP-read h.
__device__ __forceinline__ void step(float& h, float xs, const float (&w)[16],
                                     float wih, float bias) {
  float a0, a1, a2, a3;
  asm("v_fma_f32 %0, %5, %6, %7\n\t"                                      // a0 = xs*wih+bias
      "v_fmac_f32 %0, %4, %8\n\t"                                         // a0 += h*w0 (normal read)
      "v_mul_f32_dpp %1, %4, %9  row_ror:1  row_mask:0xf bank_mask:0xf\n\t"
      "v_mul_f32_dpp %2, %4, %10 row_ror:2  row_mask:0xf bank_mask:0xf\n\t"
      "v_mul_f32_dpp %3, %4, %11 row_ror:3  row_mask:0xf bank_mask:0xf\n\t"
      "v_fmac_f32_dpp %0, %4, %12 row_ror:4  row_mask:0xf bank_mask:0xf\n\t"
      "v_fmac_f32_dpp %1, %4, %13 row_ror:5  row_mask:0xf bank_mask:0xf\n\t"
      "v_fmac_f32_dpp %2, %4, %14 row_ror:6  row_mask:0xf bank_mask:0xf\n\t"
      "v_fmac_f32_dpp %3, %4, %15 row_ror:7  row_mask:0xf bank_mask:0xf\n\t"
      "v_fmac_f32_dpp %0, %4, %16 row_ror:8  row_mask:0xf bank_mask:0xf\n\t"
      "v_fmac_f32_dpp %1, %4, %17 row_ror:9  row_mask:0xf bank_mask:0xf\n\t"
      "v_fmac_f32_dpp %2, %4, %18 row_ror:10 row_mask:0xf bank_mask:0xf\n\t"
      "v_fmac_f32_dpp %3, %4, %19 row_ror:11 row_mask:0xf bank_mask:0xf\n\t"
      "v_fmac_f32_dpp %0, %4, %20 row_ror:12 row_mask:0xf bank_mask:0xf\n\t"
      "v_fmac_f32_dpp %1, %4, %21 row_ror:13 row_mask:0xf bank_mask:0xf\n\t"
      "v_fmac_f32_dpp %2, %4, %22 row_ror:14 row_mask:0xf bank_mask:0xf\n\t"
      "v_fmac_f32_dpp %3, %4, %23 row_ror:15 row_mask:0xf bank_mask:0xf\n\t"
      "v_add_f32 %0, %0, %1\n\t"
      "v_add_f32 %2, %2, %3\n\t"
      "v_add_f32 %0, %0, %2\n\t"
      "v_max_f32 %4, 0, %0"                                               // relu
      : "=&v"(a0), "=&v"(a1), "=&v"(a2), "=&v"(a3), "+v"(h)
      : "v"(xs), "v"(wih), "v"(bias),
        "v"(w[0]), "v"(w[1]), "v"(w[2]), "v"(w[3]),
        "v"(w[4]), "v"(w[5]), "v"(w[6]), "v"(w[7]),
        "v"(w[8]), "v"(w[9]), "v"(w[10]), "v"(w[11]),
        "v"(w[12]), "v"(w[13]), "v"(w[14]), "v"(w[15]));
}

// --- kernel -----------------------------------------------------------------
__global__ __launch_bounds__(256) void rnn_relu_kernel(
    const float* __restrict__ x, const float* __restrict__ W_ih,
    const float* __restrict__ b_ih, const float* __restrict__ W_hh,
    const float* __restrict__ b_hh, const float* __restrict__ W_fc,
    const float* __restrict__ b_fc, float* __restrict__ out) {
  const int tid = threadIdx.x;
  const int j   = tid & 15;                       // h index owned by this lane
  const int b   = blockIdx.x * 16 + (tid >> 4);   // batch element per 16-lane group

  // Probe row_ror:1 direction (same encoding 0x121 as asm row_ror:1):
  int pr = __builtin_amdgcn_update_dpp(0, j, 0x121, 0xF, 0xF, true);
  const bool plus = (pr == ((j + 1) & 15));

  // w[s] = W_hh[j][sigma_s(j)] so that ror_s(h)*w[s] contributes W_hh[j,k]*h[k]
  float w[16];
#pragma unroll
  for (int s = 0; s < 16; ++s) {
    int k = (j + (plus ? s : (16 - s))) & 15;
    w[s] = W_hh[j * 16 + k];
  }
  const float wih  = W_ih[j];
  const float bias = b_ih[j] + b_hh[j];

  // Each lane loads the whole 16-step x chunk for its batch row (64 B).
  // Identical addresses within the 16-lane group -> L1 broadcast; no LDS.
  const f4* __restrict__ xr = (const f4*)(x + (size_t)b * T_LEN);

  float h = 0.0f;
  f4 c0 = xr[0], c1 = xr[1], c2 = xr[2], c3 = xr[3];

#pragma unroll 1
  for (int t0 = 0; t0 < T_LEN; t0 += 16) {
    f4 n0 = {0,0,0,0}, n1 = {0,0,0,0}, n2 = {0,0,0,0}, n3 = {0,0,0,0};
    if (t0 + 16 < T_LEN) {                       // prefetch next chunk
      const f4* p = xr + ((t0 + 16) >> 2);
      n0 = p[0]; n1 = p[1]; n2 = p[2]; n3 = p[3];
    }
    step(h, c0.x, w, wih, bias);
    step(h, c0.y, w, wih, bias);
    step(h, c0.z, w, wih, bias);
    step(h, c0.w, w, wih, bias);
    step(h, c1.x, w, wih, bias);
    step(h, c1.y, w, wih, bias);
    step(h, c1.z, w, wih, bias);
    step(h, c1.w, w, wih, bias);
    step(h, c2.x, w, wih, bias);
    step(h, c2.y, w, wih, bias);
    step(h, c2.z, w, wih, bias);
    step(h, c2.w, w, wih, bias);
    step(h, c3.x, w, wih, bias);
    step(h, c3.y, w, wih, bias);
    step(h, c3.z, w, wih, bias);
    step(h, c3.w, w, wih, bias);
    c0 = n0; c1 = n1; c2 = n2; c3 = n3;
  }

  // Epilogue: out[b, c] = sum_j h[j] * W_fc[c, j] + b_fc[c]
  float p0 = h * W_fc[j];
  float p1 = h * W_fc[16 + j];
  p0 += __int_as_float(__builtin_amdgcn_ds_swizzle(__float_as_int(p0), 0x041F));
  p1 += __int_as_float(__builtin_amdgcn_ds_swizzle(__float_as_int(p1), 0x041F));
  p0 += __int_as_float(__builtin_amdgcn_ds_swizzle(__float_as_int(p0), 0x081F));
  p1 += __int_as_float(__builtin_amdgcn_ds_swizzle(__float_as_int(p1), 0x081F));
  p0 += __int_as_float(__builtin_amdgcn_ds_swizzle(__float_as_int(p0), 0x101F));
  p1 += __int_as_float(__builtin_amdgcn_ds_swizzle(__float_as_int(p1), 0x101F));
  p0 += __int_as_float(__builtin_amdgcn_ds_swizzle(__float_as_int(p0), 0x201F));
  p1 += __int_as_float(__builtin_amdgcn_ds_swizzle(__float_as_int(p1), 0x201F));

  if (j == 0) {
    out[b * 2 + 0] = p0 + b_fc[0];
    out[b * 2 + 1] = p1 + b_fc[1];
  }
}

// --- launch -----------------------------------------------------------------
extern "C" void kernel_launch(void* const* d_in, const int* in_sizes, int n_in,
                              void* d_out, int out_size, void* d_ws, size_t ws_size,
                              hipStream_t stream) {
  const float* x    = (const float*)d_in[0];
  const float* W_ih = (const float*)d_in[1];
  const float* b_ih = (const float*)d_in[2];
  const float* W_hh = (const float*)d_in[3];
  const float* b_hh = (const float*)d_in[4];
  const float* W_fc = (const float*)d_in[5];
  const float* b_fc = (const float*)d_in[6];
  float* out = (float*)d_out;

  const int B = 4096;
  dim3 grid(B / 16);    // 4096 batches / 16 per block-row group... 256 blocks
  dim3 block(256);      // 4 waves/CU -> 1 wave/SIMD (all parallelism consumed)
  hipLaunchKernelGGL(rnn_relu_kernel, grid, block, 0, stream,
                     x, W_ih, b_ih, W_hh, b_hh, W_fc, b_fc, out);
}